// Round 4
// baseline (281.937 us; speedup 1.0000x reference)
//
#include <hip/hip_runtime.h>
#include <hip/hip_bf16.h>

#define N_NODES 50000
#define N_EDGES 800000
#define IN_F 256
#define HEADS 8
#define OUT_F 32
#define HF (HEADS * OUT_F)   // 256
#define SLOPE 0.2f

typedef __attribute__((ext_vector_type(8))) short bf16x8;
typedef __attribute__((ext_vector_type(4))) float f32x4;

__device__ __forceinline__ ushort f2bf(float f) {
  union { float f; unsigned u; } x;
  x.f = f;
  unsigned r = x.u + 0x7FFFu + ((x.u >> 16) & 1u);  // RNE
  return (ushort)(r >> 16);
}
__device__ __forceinline__ float bf2f_lo(unsigned u) {
  union { unsigned u; float f; } x; x.u = u << 16; return x.f;
}
__device__ __forceinline__ float bf2f_hi(unsigned u) {
  union { unsigned u; float f; } x; x.u = u & 0xFFFF0000u; return x.f;
}

// ---------------------------------------------------------------------------
// Kernel 1: wlT[h][k] = sum_f fc_w[k, h*32+f] * attn_l[h,f]  (exact fp32)
// ---------------------------------------------------------------------------
__global__ void wl_kernel(const float* __restrict__ fc_w,
                          const float* __restrict__ attn_l,
                          float* __restrict__ wlT) {
  const int idx = blockIdx.x * blockDim.x + threadIdx.x;  // 0..2047
  const int k = idx >> 3;
  const int h = idx & 7;
  const float* fp = &fc_w[(size_t)k * HF + h * OUT_F];
  const float* ap = &attn_l[h * OUT_F];
  float acc = 0.f;
#pragma unroll
  for (int f = 0; f < OUT_F; f += 4) {
    float4 a = *(const float4*)&fp[f];
    float4 b = *(const float4*)&ap[f];
    acc += a.x * b.x + a.y * b.y + a.z * b.z + a.w * b.w;
  }
  wlT[h * IN_F + k] = acc;
}

// ---------------------------------------------------------------------------
// Kernel 2: Bt[n][k] = bf16(fc_w[k][n])  (256x256, tiny)
// ---------------------------------------------------------------------------
__global__ void transpose_w(const float* __restrict__ fc_w,
                            ushort* __restrict__ Bt) {
  const int n = blockIdx.x, k = threadIdx.x;
  Bt[n * IN_F + k] = f2bf(fc_w[(size_t)k * HF + n]);
}

// ---------------------------------------------------------------------------
// Kernel 3: fused transcode + el.  One wave per node:
//   Ab[n][k] = bf16(feat[n][k]);  el[n][h] = sum_k feat[n][k]*wlT[h][k] (fp32)
// ---------------------------------------------------------------------------
__global__ __launch_bounds__(256) void transcode_el(
    const float* __restrict__ feat, const float* __restrict__ wlT,
    ushort* __restrict__ Ab, float* __restrict__ el, int N) {
  const int wave = threadIdx.x >> 6, lane = threadIdx.x & 63;
  const int n = blockIdx.x * 4 + wave;
  if (n >= N) return;

  float4 w[HEADS];
#pragma unroll
  for (int h = 0; h < HEADS; ++h)
    w[h] = *(const float4*)&wlT[h * IN_F + lane * 4];

  float4 v = *(const float4*)&feat[(size_t)n * IN_F + lane * 4];

  union { ushort s[4]; uint2 u; } pk;
  pk.s[0] = f2bf(v.x); pk.s[1] = f2bf(v.y);
  pk.s[2] = f2bf(v.z); pk.s[3] = f2bf(v.w);
  *(uint2*)&Ab[(size_t)n * IN_F + lane * 4] = pk.u;

  float p[HEADS];
#pragma unroll
  for (int h = 0; h < HEADS; ++h)
    p[h] = v.x * w[h].x + v.y * w[h].y + v.z * w[h].z + v.w * w[h].w;
#pragma unroll
  for (int off = 32; off >= 1; off >>= 1)
#pragma unroll
    for (int h = 0; h < HEADS; ++h) p[h] += __shfl_xor(p[h], off, 64);

  if (lane < HEADS) {
    float r = p[0];
    if (lane == 1) r = p[1]; if (lane == 2) r = p[2];
    if (lane == 3) r = p[3]; if (lane == 4) r = p[4];
    if (lane == 5) r = p[5]; if (lane == 6) r = p[6];
    if (lane == 7) r = p[7];
    el[n * HEADS + lane] = r;
  }
}

// ---------------------------------------------------------------------------
// Kernel 4: bf16 MFMA GEMM  Cb[M,256] = Ab[M,256] @ Bt^T  (Bt is [n][k])
// BM=128, BN=256 (full width, A read once), BK=64, 512 threads = 8 waves,
// each wave 64x64 via 4x4 16x16x32 frags. LDS row stride 144 B (odd
// 16B-superbank stride -> conflict-free b128 fragment reads).
// ---------------------------------------------------------------------------
#define LDK 72

__global__ __launch_bounds__(512) void gemm2(const ushort* __restrict__ Ab,
                                             const ushort* __restrict__ Bt,
                                             ushort* __restrict__ Cb, int M) {
  __shared__ __align__(16) ushort As[128 * LDK];  // 18.4 KB
  __shared__ __align__(16) ushort Bs[256 * LDK];  // 36.9 KB

  const int t = threadIdx.x;
  const int wave = t >> 6, lane = t & 63;
  const int l16 = lane & 15, q = lane >> 4;
  const int m0 = blockIdx.x * 128;
  const int wm = (wave & 1) * 64;
  const int wn = (wave >> 1) * 64;

  // staging indices
  const int a_row = t >> 2;          // 0..127
  const int a_kk = (t & 3) * 16;     // ushort offset {0,16,32,48}
  const int b_n = t & 255;           // 0..255
  const int b_kk = (t >> 8) * 32;    // {0, 32}

  f32x4 acc[4][4] = {};

  for (int k0 = 0; k0 < IN_F; k0 += 64) {
    {  // A tile: 128 x 64 bf16
      uint4 v0 = {}, v1 = {};
      if (m0 + a_row < M) {
        const uint4* p = (const uint4*)&Ab[(size_t)(m0 + a_row) * IN_F + k0 + a_kk];
        v0 = p[0]; v1 = p[1];
      }
      *(uint4*)&As[a_row * LDK + a_kk] = v0;
      *(uint4*)&As[a_row * LDK + a_kk + 8] = v1;
    }
    {  // B tile: 256 x 64 bf16 (Bt rows are k-contiguous)
      const uint4* p = (const uint4*)&Bt[(size_t)b_n * IN_F + k0 + b_kk];
      uint4 b0 = p[0], b1 = p[1], b2 = p[2], b3 = p[3];
      *(uint4*)&Bs[b_n * LDK + b_kk + 0] = b0;
      *(uint4*)&Bs[b_n * LDK + b_kk + 8] = b1;
      *(uint4*)&Bs[b_n * LDK + b_kk + 16] = b2;
      *(uint4*)&Bs[b_n * LDK + b_kk + 24] = b3;
    }
    __syncthreads();
#pragma unroll
    for (int kh = 0; kh < 2; ++kh) {
      bf16x8 aF[4], bF[4];
#pragma unroll
      for (int i = 0; i < 4; ++i)
        aF[i] = *(const bf16x8*)&As[(wm + i * 16 + l16) * LDK + kh * 32 + q * 8];
#pragma unroll
      for (int j = 0; j < 4; ++j)
        bF[j] = *(const bf16x8*)&Bs[(wn + j * 16 + l16) * LDK + kh * 32 + q * 8];
#pragma unroll
      for (int i = 0; i < 4; ++i)
#pragma unroll
        for (int j = 0; j < 4; ++j)
          acc[i][j] = __builtin_amdgcn_mfma_f32_16x16x32_bf16(aF[i], bF[j],
                                                              acc[i][j], 0, 0, 0);
    }
    __syncthreads();
  }

  // epilogue: C/D layout col=l16, row=q*4+r
#pragma unroll
  for (int i = 0; i < 4; ++i) {
#pragma unroll
    for (int r = 0; r < 4; ++r) {
      const int row = m0 + wm + i * 16 + q * 4 + r;
      if (row < M) {
#pragma unroll
        for (int j = 0; j < 4; ++j) {
          const int col = wn + j * 16 + l16;
          Cb[(size_t)row * HF + col] = f2bf(acc[i][j][r]);
        }
      }
    }
  }
}

// ---------------------------------------------------------------------------
// Kernel 5: CSR row_ptr from sorted dst via binary search
// ---------------------------------------------------------------------------
__global__ void rowptr_kernel(const int* __restrict__ dst,
                              int* __restrict__ row_ptr, int N, int E) {
  int i = blockIdx.x * blockDim.x + threadIdx.x;
  if (i > N) return;
  int lo = 0, hi = E;
  while (lo < hi) {
    int mid = (lo + hi) >> 1;
    if (dst[mid] < i) lo = mid + 1; else hi = mid;
  }
  row_ptr[i] = lo;
}

// ---------------------------------------------------------------------------
// Kernel 6: per-destination softmax + aggregation, wide gathers.
// 256 threads/node. Feature pass: half-wave (32 lanes x uint4 = 512 B) per
// edge row -> 8 edges per block-step, facc[8] per lane, shfl+LDS reduce.
// ---------------------------------------------------------------------------
#define CAP 128

__global__ __launch_bounds__(256) void aggregate_kernel(
    const ushort* __restrict__ featb, const float* __restrict__ el,
    const int* __restrict__ src, const int* __restrict__ row_ptr,
    float* __restrict__ out) {
  const int v = blockIdx.x;
  const int t = threadIdx.x;
  const int lane = t & 63, wave = t >> 6;
  const int beg = row_ptr[v];
  const int deg = row_ptr[v + 1] - beg;

  if (deg == 0) {
    out[(size_t)v * HF + t] = 0.f;
    return;
  }

  __shared__ float s_el[CAP][HEADS];     // 4 KB
  __shared__ int s_src[CAP];             // 0.5 KB
  __shared__ float s_alpha[CAP][HEADS];  // 4 KB
  __shared__ float s_part[32][HEADS];    // 1 KB
  __shared__ float s_m[HEADS];
  __shared__ float s_inv[HEADS];
  __shared__ float s_red[4][HF];         // 4 KB

  const int h8 = t & 7;
  const int j = t >> 3;  // 0..31

  // Phase 1: gather el (+src) into LDS (c<CAP), compute running max
  float mx = -1e30f;
  for (int c = j; c < deg; c += 32) {
    int s = src[beg + c];
    float e = el[s * HEADS + h8];
    if (c < CAP) {
      s_el[c][h8] = e;
      if (h8 == 0) s_src[c] = s;
    }
    mx = fmaxf(mx, e);
  }
  s_part[j][h8] = mx;
  __syncthreads();
  if (t < HEADS) {
    float m = s_part[0][t];
#pragma unroll
    for (int jj = 1; jj < 32; ++jj) m = fmaxf(m, s_part[jj][t]);
    s_m[t] = m;
  }
  __syncthreads();
  const float m = s_m[h8];

  // feature-pass lane mapping
  const int myh = (lane & 31) >> 2;       // head of this lane's 8 elems
  const int fo = (lane & 31) * 8;         // element base (0..248)
  const int eoff = wave * 2 + (lane >> 5);  // 0..7: edge slot in a step
  float facc[8] = {};
  float ssum = 0.f;

  for (int c0 = 0; c0 < deg; c0 += CAP) {
    const int cn = min(CAP, deg - c0);
    const int cpad = (cn + 7) & ~7;

    if (c0 == 0) {  // common path: alphas from LDS-cached el
      for (int c = j; c < cn; c += 32) {
        float z = s_el[c][h8] - m;
        float w = (z >= 0.f) ? z : SLOPE * z;
        float cf = __expf(w);
        s_alpha[c][h8] = cf;
        ssum += cf;
      }
    } else {  // rare chunked path: re-gather from global
      __syncthreads();
      for (int c = j; c < cn; c += 32) {
        int s = src[beg + c0 + c];
        if (h8 == 0) s_src[c] = s;
        float z = el[s * HEADS + h8] - m;
        float w = (z >= 0.f) ? z : SLOPE * z;
        float cf = __expf(w);
        s_alpha[c][h8] = cf;
        ssum += cf;
      }
    }
    if (j < 8) {  // zero the pad slots (alpha=0, src=0 -> contributes 0)
      int c = cn + j;
      if (c < cpad) {
        s_alpha[c][h8] = 0.f;
        if (h8 == 0) s_src[c] = 0;
      }
    }
    __syncthreads();

    for (int c = eoff; c < cpad; c += 8) {
      const int sc = s_src[c];
      const float a = s_alpha[c][myh];
      const uint4 d = *(const uint4*)&featb[(size_t)sc * HF + fo];
      facc[0] = fmaf(a, bf2f_lo(d.x), facc[0]);
      facc[1] = fmaf(a, bf2f_hi(d.x), facc[1]);
      facc[2] = fmaf(a, bf2f_lo(d.y), facc[2]);
      facc[3] = fmaf(a, bf2f_hi(d.y), facc[3]);
      facc[4] = fmaf(a, bf2f_lo(d.z), facc[4]);
      facc[5] = fmaf(a, bf2f_hi(d.z), facc[5]);
      facc[6] = fmaf(a, bf2f_lo(d.w), facc[6]);
      facc[7] = fmaf(a, bf2f_hi(d.w), facc[7]);
    }
    __syncthreads();
  }

  // softmax denominator
  s_part[j][h8] = ssum;
  __syncthreads();
  if (t < HEADS) {
    float a = 0.f;
#pragma unroll
    for (int jj = 0; jj < 32; ++jj) a += s_part[jj][t];
    s_inv[t] = 1.0f / a;
  }

  // combine half-waves (partner lane^32 holds same elems, other edges)
#pragma unroll
  for (int i = 0; i < 8; ++i) facc[i] += __shfl_xor(facc[i], 32, 64);
  if (lane < 32) {
    *(float4*)&s_red[wave][fo] = make_float4(facc[0], facc[1], facc[2], facc[3]);
    *(float4*)&s_red[wave][fo + 4] = make_float4(facc[4], facc[5], facc[6], facc[7]);
  }
  __syncthreads();

  const float o = s_red[0][t] + s_red[1][t] + s_red[2][t] + s_red[3][t];
  out[(size_t)v * HF + t] = o * s_inv[t >> 5];
}

// ---------------------------------------------------------------------------
extern "C" void kernel_launch(void* const* d_in, const int* in_sizes, int n_in,
                              void* d_out, int out_size, void* d_ws,
                              size_t ws_size, hipStream_t stream) {
  const float* feat = (const float*)d_in[0];
  const float* fc_w = (const float*)d_in[1];
  const float* attn_l = (const float*)d_in[2];
  // d_in[3] = attn_r: unused — cancels exactly in the edge softmax.
  const int* src = (const int*)d_in[4];
  const int* dst = (const int*)d_in[5];
  float* out = (float*)d_out;

  const int N = N_NODES;
  const int E = N_EDGES;

  // Transient bf16 copy of feat lives in d_out (legal scratch: stream order
  // is transcode_el[writes Ab] -> gemm2[reads Ab] -> aggregate[writes out]).
  ushort* Ab = (ushort*)d_out;                      // N*256 bf16 (25.6 MB)

  // workspace layout (~27.8 MB, well within proven ws_size)
  ushort* featb = (ushort*)d_ws;                    // N*256 bf16  (25.6 MB)
  float* el = (float*)(featb + (size_t)N * HF);     // N*8 f32     (1.6 MB)
  float* wlT = el + (size_t)N * HEADS;              // 8*256 f32
  ushort* Bt = (ushort*)(wlT + HEADS * IN_F);       // 256*256 bf16
  int* row_ptr = (int*)(Bt + (size_t)IN_F * HF);    // N+1 ints

  wl_kernel<<<(IN_F * HEADS) / 256, 256, 0, stream>>>(fc_w, attn_l, wlT);
  transpose_w<<<HF, IN_F, 0, stream>>>(fc_w, Bt);
  transcode_el<<<(N + 3) / 4, 256, 0, stream>>>(feat, wlT, Ab, el, N);
  gemm2<<<(N + 127) / 128, 512, 0, stream>>>(Ab, Bt, featb, N);
  rowptr_kernel<<<(N + 1 + 255) / 256, 256, 0, stream>>>(dst, row_ptr, N, E);
  aggregate_kernel<<<N, 256, 0, stream>>>(featb, el, src, row_ptr, out);
}